// Round 3
// baseline (401.434 us; speedup 1.0000x reference)
//
#include <hip/hip_runtime.h>

// ---------------------------------------------------------------------------
// Column-softmax self-attention, bf16 MFMA pipeline, latency-optimized.
//   S'[d,t] = k_d . q_t * (log2e/8)   (scale folded into Q projection)
//   P[d,t]  = exp2(S')/s_d,  s_d = sum_t exp2(S'[d,t])   (no max: |S| small)
//   out[t,e] = sum_d exp2(S'[d,t]) * V'[d,e],  V'[d,e] = v[d,e]/s_d
// MFMA 16x16x32 bf16 layouts:
//   A: lane holds A[m=lane%16][k=(lane/16)*8+j]
//   B: lane holds B[k=(lane/16)*8+j][n=lane%16]  (loaded from [n][k] storage)
//   C/D: lane holds D[row=(lane/16)*4+r][col=lane%16]
// ---------------------------------------------------------------------------

typedef __attribute__((ext_vector_type(8))) __bf16 bf16x8;
typedef __attribute__((ext_vector_type(8))) unsigned short ushort8;
typedef __attribute__((ext_vector_type(4))) float f32x4;
typedef unsigned int uint32;

constexpr int B_ = 4;
constexpr int T_ = 2048;
constexpr int H_ = 8;
constexpr int E_ = 64;
constexpr int BH_ = B_ * H_;
constexpr int SZ_ = 8;  // stats t-split factor
constexpr float QSCALE_ = 0.125f * 1.4426950408889634f;  // 1/sqrt(64) * log2(e)

__device__ inline uint32 f2bf1(float f) {  // fp32 -> bf16 bits, RNE
  uint32 u = __builtin_bit_cast(uint32, f);
  return (u + 0x7fffu + ((u >> 16) & 1u)) >> 16;
}
__device__ inline uint32 pk2(float a, float b) {
  return f2bf1(a) | (f2bf1(b) << 16);
}
__device__ inline float bf2f(uint32 bits) {
  return __builtin_bit_cast(float, bits << 16);
}
__device__ inline bf16x8 ld8(const unsigned short* p) {
  return __builtin_bit_cast(bf16x8, *(const ushort8*)p);
}
#define MFMA16(a, b, c) __builtin_amdgcn_mfma_f32_16x16x32_bf16(a, b, c, 0, 0, 0)
#define EXP2(x) __builtin_amdgcn_exp2f(x)

// ---- fused projections: grid.y = 0(Q) / 1(K) / 2(V); output bf16 (b,h,t,e)
__global__ __launch_bounds__(512) void proj_kernel(
    const float* __restrict__ Xq, const float* __restrict__ Xk,
    const float* __restrict__ Xv, const float* __restrict__ Wq,
    const float* __restrict__ Wk, const float* __restrict__ Wv,
    unsigned short* __restrict__ Yq, unsigned short* __restrict__ Yk,
    unsigned short* __restrict__ Yv) {
  constexpr int RT = 8;
  __shared__ float xs[RT][E_];
  const int z = blockIdx.y;
  const float* X = (z == 0) ? Xq : (z == 1) ? Xk : Xv;
  const float* W = (z == 0) ? Wq : (z == 1) ? Wk : Wv;
  unsigned short* Y = (z == 0) ? Yq : (z == 1) ? Yk : Yv;
  const float scale = (z == 0) ? QSCALE_ : 1.0f;
  const int row0 = blockIdx.x * RT;  // row = b*T + t
  const int tid = threadIdx.x;
  {
    const int r = tid >> 6, c = tid & 63;
    xs[r][c] = X[(row0 + r) * E_ + c];
  }
  __syncthreads();
  const int j = tid;
  const int h = j >> 6, e = j & 63;
  float acc[RT];
#pragma unroll
  for (int r = 0; r < RT; ++r) acc[r] = 0.f;
  for (int c = 0; c < E_; ++c) {
    const float w = W[c * (H_ * E_) + j];
#pragma unroll
    for (int r = 0; r < RT; ++r) acc[r] += xs[r][c] * w;
  }
#pragma unroll
  for (int r = 0; r < RT; ++r) {
    const int row = row0 + r;
    const int b = row >> 11, t = row & (T_ - 1);
    Y[(((size_t)(b * H_ + h) * T_ + t) << 6) + e] =
        (unsigned short)f2bf1(acc[r] * scale);
  }
}

// ---- pass A (t-split): s_part[z][bh][d] = sum_{t in slice} exp2(S'[d,t])
__global__ __launch_bounds__(256, 4) void stats_kernel(
    const unsigned short* __restrict__ K16, const unsigned short* __restrict__ Q16,
    float* __restrict__ s_part) {
  const int bh = blockIdx.y;
  const int tid = threadIdx.x;
  const int w = tid >> 6, lane = tid & 63;
  const int lm = lane & 15, lq = lane >> 4;
  const int d0 = blockIdx.x * 256 + w * 64;
  const int tz0 = blockIdx.z * (T_ / SZ_);
  const int tzend = tz0 + (T_ / SZ_);
  const unsigned short* Kp = K16 + (size_t)bh * T_ * E_;
  const unsigned short* Qp = Q16 + (size_t)bh * T_ * E_;

  bf16x8 kf[4][2];  // loop-invariant K fragments (64 d rows)
#pragma unroll
  for (int dt = 0; dt < 4; ++dt) {
    kf[dt][0] = ld8(&Kp[(size_t)(d0 + dt * 16 + lm) * E_ + lq * 8]);
    kf[dt][1] = ld8(&Kp[(size_t)(d0 + dt * 16 + lm) * E_ + 32 + lq * 8]);
  }
  f32x4 sacc[4];
#pragma unroll
  for (int dt = 0; dt < 4; ++dt) sacc[dt] = (f32x4){0.f, 0.f, 0.f, 0.f};
  const f32x4 zero = {0.f, 0.f, 0.f, 0.f};

  // register double-buffered Q sweep over this t-slice
  bf16x8 ql = ld8(&Qp[(size_t)(tz0 + lm) * E_ + lq * 8]);
  bf16x8 qh = ld8(&Qp[(size_t)(tz0 + lm) * E_ + 32 + lq * 8]);
  for (int t0 = tz0; t0 < tzend; t0 += 16) {
    const int tn = (t0 + 16 < tzend) ? t0 + 16 : tz0;
    bf16x8 nl = ld8(&Qp[(size_t)(tn + lm) * E_ + lq * 8]);
    bf16x8 nh = ld8(&Qp[(size_t)(tn + lm) * E_ + 32 + lq * 8]);
#pragma unroll
    for (int dt = 0; dt < 4; ++dt) {
      f32x4 c = MFMA16(kf[dt][0], ql, zero);
      c = MFMA16(kf[dt][1], qh, c);
#pragma unroll
      for (int r = 0; r < 4; ++r) sacc[dt][r] += EXP2(c[r]);
    }
    ql = nl; qh = nh;
  }
  // reduce over the 16 column-lanes (t within tile)
#pragma unroll
  for (int m = 1; m < 16; m <<= 1) {
#pragma unroll
    for (int dt = 0; dt < 4; ++dt)
#pragma unroll
      for (int r = 0; r < 4; ++r)
        sacc[dt][r] += __shfl_xor(sacc[dt][r], m);
  }
  if (lm == 0) {
#pragma unroll
    for (int dt = 0; dt < 4; ++dt)
#pragma unroll
      for (int r = 0; r < 4; ++r)
        s_part[((size_t)blockIdx.z * BH_ + bh) * T_ + d0 + dt * 16 + lq * 4 + r] =
            sacc[dt][r];
  }
}

// ---- scale+transpose: Vt[bh][e][d] = v_bf[bh][d][e] / s_d  (bf16)
__global__ __launch_bounds__(256) void scale_kernel(
    const unsigned short* __restrict__ V16, const float* __restrict__ s_part,
    unsigned short* __restrict__ Vt16) {
  __shared__ float ts[64][68];
  __shared__ float sinv_s[64];
  const int bh = blockIdx.y;
  const int d0 = blockIdx.x * 64;
  const unsigned short* Vp = V16 + (size_t)bh * T_ * E_;
  const int tid = threadIdx.x;
  if (tid < 64) {
    float s = 0.f;
#pragma unroll
    for (int z = 0; z < SZ_; ++z)
      s += s_part[((size_t)z * BH_ + bh) * T_ + d0 + tid];
    sinv_s[tid] = 1.0f / s;
  }
  __syncthreads();
  for (int idx = tid; idx < 64 * 8; idx += 256) {
    const int r = idx >> 3, c8 = idx & 7;
    const ushort8 v8 = *(const ushort8*)&Vp[(size_t)(d0 + r) * E_ + c8 * 8];
    const float is = sinv_s[r];
#pragma unroll
    for (int k = 0; k < 8; ++k) ts[r][c8 * 8 + k] = bf2f(v8[k]) * is;
  }
  __syncthreads();
  for (int idx = tid; idx < 64 * 16; idx += 256) {
    const int e = idx >> 4, d4 = idx & 15;
    uint2 o;
    o.x = pk2(ts[d4 * 4 + 0][e], ts[d4 * 4 + 1][e]);
    o.y = pk2(ts[d4 * 4 + 2][e], ts[d4 * 4 + 3][e]);
    *(uint2*)&Vt16[((size_t)bh * E_ + e) * T_ + d0 + d4 * 4] = o;
  }
}

// ---- pass B: O[t,e] = sum_d exp2(S'[d,t]) * V'[d,e]; wave owns 16 t x 64 e
__global__ __launch_bounds__(256, 4) void apply_kernel(
    const unsigned short* __restrict__ K16, const unsigned short* __restrict__ Q16,
    const unsigned short* __restrict__ Vt16, float* __restrict__ o_ws) {
  __shared__ __attribute__((aligned(16))) unsigned short es[4][16][40];
  const int bh = blockIdx.y;
  const int b = bh >> 3, h = bh & 7;
  const int tid = threadIdx.x;
  const int w = tid >> 6, lane = tid & 63;
  const int lm = lane & 15, lq = lane >> 4;
  const int t0 = blockIdx.x * 64 + w * 16;
  const unsigned short* Kp = K16 + (size_t)bh * T_ * E_;
  const unsigned short* Qp = Q16 + (size_t)bh * T_ * E_;
  const unsigned short* Vp = Vt16 + (size_t)bh * E_ * T_;

  // loop-invariant Q fragments (B operand, n = t)
  const bf16x8 qf0 = ld8(&Qp[(size_t)(t0 + lm) * E_ + lq * 8]);
  const bf16x8 qf1 = ld8(&Qp[(size_t)(t0 + lm) * E_ + 32 + lq * 8]);
  f32x4 acc[4];
#pragma unroll
  for (int ec = 0; ec < 4; ++ec) acc[ec] = (f32x4){0.f, 0.f, 0.f, 0.f};
  const f32x4 zero = {0.f, 0.f, 0.f, 0.f};

  // prime register double-buffer (d-chunk 0)
  bf16x8 ck0l = ld8(&Kp[(size_t)lm * E_ + lq * 8]);
  bf16x8 ck0h = ld8(&Kp[(size_t)lm * E_ + 32 + lq * 8]);
  bf16x8 ck1l = ld8(&Kp[(size_t)(16 + lm) * E_ + lq * 8]);
  bf16x8 ck1h = ld8(&Kp[(size_t)(16 + lm) * E_ + 32 + lq * 8]);
  bf16x8 cv[4];
#pragma unroll
  for (int ec = 0; ec < 4; ++ec)
    cv[ec] = ld8(&Vp[(size_t)(ec * 16 + lm) * T_ + lq * 8]);

  for (int d0 = 0; d0 < T_; d0 += 32) {
    const int dn = (d0 + 32) & (T_ - 1);  // wraps on last iter (harmless reload)
    bf16x8 nk0l = ld8(&Kp[(size_t)(dn + lm) * E_ + lq * 8]);
    bf16x8 nk0h = ld8(&Kp[(size_t)(dn + lm) * E_ + 32 + lq * 8]);
    bf16x8 nk1l = ld8(&Kp[(size_t)(dn + 16 + lm) * E_ + lq * 8]);
    bf16x8 nk1h = ld8(&Kp[(size_t)(dn + 16 + lm) * E_ + 32 + lq * 8]);
    bf16x8 nv[4];
#pragma unroll
    for (int ec = 0; ec < 4; ++ec)
      nv[ec] = ld8(&Vp[(size_t)(ec * 16 + lm) * T_ + dn + lq * 8]);

    // S' tiles: c0 covers d in [d0,d0+16), c1 covers [d0+16,d0+32)
    f32x4 c0 = MFMA16(ck0l, qf0, zero);
    c0 = MFMA16(ck0h, qf1, c0);
    f32x4 c1 = MFMA16(ck1l, qf0, zero);
    c1 = MFMA16(ck1h, qf1, c1);
    float e0[4], e1[4];
#pragma unroll
    for (int r = 0; r < 4; ++r) { e0[r] = EXP2(c0[r]); e1[r] = EXP2(c1[r]); }
    // store transposed: es[t=lm][d]
    *(uint2*)&es[w][lm][lq * 4] = make_uint2(pk2(e0[0], e0[1]), pk2(e0[2], e0[3]));
    *(uint2*)&es[w][lm][16 + lq * 4] = make_uint2(pk2(e1[0], e1[1]), pk2(e1[2], e1[3]));
    asm volatile("s_waitcnt lgkmcnt(0)" ::: "memory");  // wave-private LDS
    const bf16x8 ae = ld8(&es[w][lm][lq * 8]);  // A: [m=t][k=d]
#pragma unroll
    for (int ec = 0; ec < 4; ++ec) acc[ec] = MFMA16(ae, cv[ec], acc[ec]);

    ck0l = nk0l; ck0h = nk0h; ck1l = nk1l; ck1h = nk1h;
#pragma unroll
    for (int ec = 0; ec < 4; ++ec) cv[ec] = nv[ec];
  }

  // epilogue: o_ws in (b,t,h,e) fp32
#pragma unroll
  for (int ec = 0; ec < 4; ++ec) {
    const int e = ec * 16 + lm;
    float* op = &o_ws[((size_t)(b * T_ + t0 + lq * 4) * H_ + h) * E_ + e];
#pragma unroll
    for (int r = 0; r < 4; ++r) op[(size_t)r * H_ * E_] = acc[ec][r];
  }
}

// ---- unify: out[row, j] = sum_c o_ws[row, c] * Wu[c, j] + bu[j]
__global__ __launch_bounds__(256) void unify_kernel(
    const float* __restrict__ o_ws, const float* __restrict__ Wu,
    const float* __restrict__ bu, float* __restrict__ out) {
  constexpr int RT = 16;
  __shared__ float xs[RT][H_ * E_];
  const int row0 = blockIdx.x * RT;
  const int tid = threadIdx.x;
  for (int idx = tid; idx < RT * 128; idx += 256) {
    const int r = idx >> 7, c4 = idx & 127;
    *(float4*)&xs[r][c4 * 4] = *(const float4*)&o_ws[(size_t)(row0 + r) * 512 + c4 * 4];
  }
  __syncthreads();
  const int j = tid & 63;
  const int rg = tid >> 6;
  float acc[4] = {0.f, 0.f, 0.f, 0.f};
  for (int c = 0; c < 512; ++c) {
    const float w = Wu[c * 64 + j];
#pragma unroll
    for (int r = 0; r < 4; ++r) acc[r] += xs[rg * 4 + r][c] * w;
  }
  const float bias = bu[j];
#pragma unroll
  for (int r = 0; r < 4; ++r)
    out[(size_t)(row0 + rg * 4 + r) * 64 + j] = acc[r] + bias;
}

extern "C" void kernel_launch(void* const* d_in, const int* in_sizes, int n_in,
                              void* d_out, int out_size, void* d_ws, size_t ws_size,
                              hipStream_t stream) {
  const float* values  = (const float*)d_in[0];
  const float* keys    = (const float*)d_in[1];
  const float* queries = (const float*)d_in[2];
  const float* Wv      = (const float*)d_in[3];
  const float* Wk      = (const float*)d_in[4];
  const float* Wq      = (const float*)d_in[5];
  const float* Wu      = (const float*)d_in[6];
  const float* bu      = (const float*)d_in[7];
  float* out = (float*)d_out;

  const size_t NQ = (size_t)BH_ * T_ * E_;  // 4.19M elements
  unsigned short* q_bf  = (unsigned short*)d_ws;
  unsigned short* k_bf  = q_bf + NQ;
  unsigned short* v_bf  = k_bf + NQ;
  unsigned short* vt_bf = v_bf + NQ;
  float* o_ws   = (float*)(vt_bf + NQ);
  float* s_part = o_ws + NQ;  // SZ_ * BH_ * T_ floats

  proj_kernel<<<dim3(B_ * T_ / 8, 3), 512, 0, stream>>>(
      queries, keys, values, Wq, Wk, Wv, q_bf, k_bf, v_bf);
  stats_kernel<<<dim3(T_ / 256, BH_, SZ_), 256, 0, stream>>>(k_bf, q_bf, s_part);
  scale_kernel<<<dim3(T_ / 64, BH_), 256, 0, stream>>>(v_bf, s_part, vt_bf);
  apply_kernel<<<dim3(T_ / 64, BH_), 256, 0, stream>>>(k_bf, q_bf, vt_bf, o_ws);
  unify_kernel<<<B_ * T_ / 16, 256, 0, stream>>>(o_ws, Wu, bu, out);
}

// Round 4
// 391.775 us; speedup vs baseline: 1.0247x; 1.0247x over previous
//
#include <hip/hip_runtime.h>

// ---------------------------------------------------------------------------
// Column-softmax self-attention, bf16 MFMA pipeline.
//   S'[d,t] = k_d . q_t * (log2e/8)   (scale folded into Q projection)
//   P[d,t]  = exp2(S')/s_d,  s_d = sum_t exp2(S'[d,t])   (no max: |S| small)
//   O^T[e,t] = sum_d V'^T[e,d] * exp2(S'[d,t]),  V'[d,e] = v[d,e]/s_d
// Layout trick (apply kernel): C/D layout of 16x16 MFMA (row=lq*4+r, col=lm)
// IS the B-operand layout of v_mfma_f32_16x16x16_bf16 (k=lq*4+j, n=lm).
// Compute S with m=d, n=t -> exp2(S) fragments are directly the B operand of
// the PV MFMA (k=d, n=t), A = V'^T from Vt16[e][d]. Zero LDS, zero shuffles.
// ---------------------------------------------------------------------------

typedef __attribute__((ext_vector_type(8))) __bf16 bf16x8;
typedef __attribute__((ext_vector_type(8))) unsigned short ushort8;
typedef __attribute__((ext_vector_type(4))) unsigned short ushort4v;
typedef __attribute__((ext_vector_type(4))) short short4v;
typedef __attribute__((ext_vector_type(4))) float f32x4;
typedef unsigned int uint32;

constexpr int B_ = 4;
constexpr int T_ = 2048;
constexpr int H_ = 8;
constexpr int E_ = 64;
constexpr int BH_ = B_ * H_;
constexpr int SZ_ = 8;  // stats t-split factor
constexpr float QSCALE_ = 0.125f * 1.4426950408889634f;  // 1/sqrt(64) * log2(e)

__device__ inline uint32 f2bf1(float f) {  // fp32 -> bf16 bits, RNE
  uint32 u = __builtin_bit_cast(uint32, f);
  return (u + 0x7fffu + ((u >> 16) & 1u)) >> 16;
}
__device__ inline uint32 pk2(float a, float b) {
  return f2bf1(a) | (f2bf1(b) << 16);
}
__device__ inline float bf2f(uint32 bits) {
  return __builtin_bit_cast(float, bits << 16);
}
__device__ inline bf16x8 ld8(const unsigned short* p) {
  return __builtin_bit_cast(bf16x8, *(const ushort8*)p);
}
__device__ inline short4v ld4(const unsigned short* p) {
  return __builtin_bit_cast(short4v, *(const ushort4v*)p);
}
#define MFMA16(a, b, c) __builtin_amdgcn_mfma_f32_16x16x32_bf16(a, b, c, 0, 0, 0)
#define EXP2(x) __builtin_amdgcn_exp2f(x)

// k=16 bf16 MFMA (PV step): A,B are 4 bf16 (2 VGPRs) each
__device__ inline f32x4 pv_mfma(short4v a, short4v b, f32x4 c) {
#if __has_builtin(__builtin_amdgcn_mfma_f32_16x16x16bf16_1k)
  return __builtin_amdgcn_mfma_f32_16x16x16bf16_1k(a, b, c, 0, 0, 0);
#else
  asm("v_mfma_f32_16x16x16_bf16 %0, %1, %2, %0" : "+v"(c) : "v"(a), "v"(b));
  return c;
#endif
}

// ---- fused projections: grid.y = 0(Q) / 1(K) / 2(V); output bf16 (b,h,t,e)
__global__ __launch_bounds__(512) void proj_kernel(
    const float* __restrict__ Xq, const float* __restrict__ Xk,
    const float* __restrict__ Xv, const float* __restrict__ Wq,
    const float* __restrict__ Wk, const float* __restrict__ Wv,
    unsigned short* __restrict__ Yq, unsigned short* __restrict__ Yk,
    unsigned short* __restrict__ Yv) {
  constexpr int RT = 8;
  __shared__ float xs[RT][E_];
  const int z = blockIdx.y;
  const float* X = (z == 0) ? Xq : (z == 1) ? Xk : Xv;
  const float* W = (z == 0) ? Wq : (z == 1) ? Wk : Wv;
  unsigned short* Y = (z == 0) ? Yq : (z == 1) ? Yk : Yv;
  const float scale = (z == 0) ? QSCALE_ : 1.0f;
  const int row0 = blockIdx.x * RT;  // row = b*T + t
  const int tid = threadIdx.x;
  {
    const int r = tid >> 6, c = tid & 63;
    xs[r][c] = X[(row0 + r) * E_ + c];
  }
  __syncthreads();
  const int j = tid;
  const int h = j >> 6, e = j & 63;
  float acc[RT];
#pragma unroll
  for (int r = 0; r < RT; ++r) acc[r] = 0.f;
  for (int c = 0; c < E_; ++c) {
    const float w = W[c * (H_ * E_) + j];
#pragma unroll
    for (int r = 0; r < RT; ++r) acc[r] += xs[r][c] * w;
  }
#pragma unroll
  for (int r = 0; r < RT; ++r) {
    const int row = row0 + r;
    const int b = row >> 11, t = row & (T_ - 1);
    Y[(((size_t)(b * H_ + h) * T_ + t) << 6) + e] =
        (unsigned short)f2bf1(acc[r] * scale);
  }
}

// ---- pass A (t-split): s_part[z][bh][d] = sum_{t in slice} exp2(S'[d,t])
__global__ __launch_bounds__(256, 4) void stats_kernel(
    const unsigned short* __restrict__ K16, const unsigned short* __restrict__ Q16,
    float* __restrict__ s_part) {
  const int bh = blockIdx.y;
  const int tid = threadIdx.x;
  const int w = tid >> 6, lane = tid & 63;
  const int lm = lane & 15, lq = lane >> 4;
  const int d0 = blockIdx.x * 256 + w * 64;
  const int tz0 = blockIdx.z * (T_ / SZ_);
  const int tzend = tz0 + (T_ / SZ_);
  const unsigned short* Kp = K16 + (size_t)bh * T_ * E_;
  const unsigned short* Qp = Q16 + (size_t)bh * T_ * E_;

  bf16x8 kf[4][2];  // loop-invariant K fragments (64 d rows)
#pragma unroll
  for (int dt = 0; dt < 4; ++dt) {
    kf[dt][0] = ld8(&Kp[(size_t)(d0 + dt * 16 + lm) * E_ + lq * 8]);
    kf[dt][1] = ld8(&Kp[(size_t)(d0 + dt * 16 + lm) * E_ + 32 + lq * 8]);
  }
  f32x4 sacc[4];
#pragma unroll
  for (int dt = 0; dt < 4; ++dt) sacc[dt] = (f32x4){0.f, 0.f, 0.f, 0.f};
  const f32x4 zero = {0.f, 0.f, 0.f, 0.f};

  for (int t0 = tz0; t0 < tzend; t0 += 16) {
    const bf16x8 ql = ld8(&Qp[(size_t)(t0 + lm) * E_ + lq * 8]);
    const bf16x8 qh = ld8(&Qp[(size_t)(t0 + lm) * E_ + 32 + lq * 8]);
#pragma unroll
    for (int dt = 0; dt < 4; ++dt) {
      f32x4 c = MFMA16(kf[dt][0], ql, zero);
      c = MFMA16(kf[dt][1], qh, c);
#pragma unroll
      for (int r = 0; r < 4; ++r) sacc[dt][r] += EXP2(c[r]);
    }
  }
  // reduce over the 16 column-lanes (t within tile)
#pragma unroll
  for (int m = 1; m < 16; m <<= 1) {
#pragma unroll
    for (int dt = 0; dt < 4; ++dt)
#pragma unroll
      for (int r = 0; r < 4; ++r)
        sacc[dt][r] += __shfl_xor(sacc[dt][r], m);
  }
  if (lm == 0) {
#pragma unroll
    for (int dt = 0; dt < 4; ++dt)
#pragma unroll
      for (int r = 0; r < 4; ++r)
        s_part[((size_t)blockIdx.z * BH_ + bh) * T_ + d0 + dt * 16 + lq * 4 + r] =
            sacc[dt][r];
  }
}

// ---- scale+transpose: Vt[bh][e][d] = v_bf[bh][d][e] / s_d  (bf16)
__global__ __launch_bounds__(256) void scale_kernel(
    const unsigned short* __restrict__ V16, const float* __restrict__ s_part,
    unsigned short* __restrict__ Vt16) {
  __shared__ float ts[64][68];
  __shared__ float sinv_s[64];
  const int bh = blockIdx.y;
  const int d0 = blockIdx.x * 64;
  const unsigned short* Vp = V16 + (size_t)bh * T_ * E_;
  const int tid = threadIdx.x;
  if (tid < 64) {
    float s = 0.f;
#pragma unroll
    for (int z = 0; z < SZ_; ++z)
      s += s_part[((size_t)z * BH_ + bh) * T_ + d0 + tid];
    sinv_s[tid] = 1.0f / s;
  }
  __syncthreads();
  for (int idx = tid; idx < 64 * 8; idx += 256) {
    const int r = idx >> 3, c8 = idx & 7;
    const ushort8 v8 = *(const ushort8*)&Vp[(size_t)(d0 + r) * E_ + c8 * 8];
    const float is = sinv_s[r];
#pragma unroll
    for (int k = 0; k < 8; ++k) ts[r][c8 * 8 + k] = bf2f(v8[k]) * is;
  }
  __syncthreads();
  for (int idx = tid; idx < 64 * 16; idx += 256) {
    const int e = idx >> 4, d4 = idx & 15;
    uint2 o;
    o.x = pk2(ts[d4 * 4 + 0][e], ts[d4 * 4 + 1][e]);
    o.y = pk2(ts[d4 * 4 + 2][e], ts[d4 * 4 + 3][e]);
    *(uint2*)&Vt16[((size_t)bh * E_ + e) * T_ + d0 + d4 * 4] = o;
  }
}

// ---- pass B: O^T[e,t] = sum_d V'^T[e,d] exp2(S'[d,t]); wave: 32 t x 64 e
// No LDS, no barriers: exp2(S) C-fragments feed PV MFMAs as B operands.
__global__ __launch_bounds__(256, 2) void apply_kernel(
    const unsigned short* __restrict__ K16, const unsigned short* __restrict__ Q16,
    const unsigned short* __restrict__ Vt16, float* __restrict__ o_ws) {
  const int bh = blockIdx.y;
  const int b = bh >> 3, h = bh & 7;
  const int tid = threadIdx.x;
  const int w = tid >> 6, lane = tid & 63;
  const int lm = lane & 15, lq = lane >> 4;
  const int t0 = blockIdx.x * 128 + w * 32;
  const unsigned short* Kp = K16 + (size_t)bh * T_ * E_;
  const unsigned short* Qp = Q16 + (size_t)bh * T_ * E_;
  const unsigned short* Vp = Vt16 + (size_t)bh * E_ * T_;

  // loop-invariant Q fragments (B operand of S-MFMA: k=e, n=t)
  bf16x8 qf[2][2];
#pragma unroll
  for (int tt = 0; tt < 2; ++tt) {
    qf[tt][0] = ld8(&Qp[(size_t)(t0 + tt * 16 + lm) * E_ + lq * 8]);
    qf[tt][1] = ld8(&Qp[(size_t)(t0 + tt * 16 + lm) * E_ + 32 + lq * 8]);
  }
  f32x4 acc[2][4];  // O^T[e = ec*16 + lq*4 + r][t = t0 + tt*16 + lm]
#pragma unroll
  for (int tt = 0; tt < 2; ++tt)
#pragma unroll
    for (int ec = 0; ec < 4; ++ec) acc[tt][ec] = (f32x4){0.f, 0.f, 0.f, 0.f};
  const f32x4 zero = {0.f, 0.f, 0.f, 0.f};

  for (int d0 = 0; d0 < T_; d0 += 32) {
    // K A-frags for S: A[m = d][k = e]
    const bf16x8 k00 = ld8(&Kp[(size_t)(d0 + lm) * E_ + lq * 8]);
    const bf16x8 k01 = ld8(&Kp[(size_t)(d0 + lm) * E_ + 32 + lq * 8]);
    const bf16x8 k10 = ld8(&Kp[(size_t)(d0 + 16 + lm) * E_ + lq * 8]);
    const bf16x8 k11 = ld8(&Kp[(size_t)(d0 + 16 + lm) * E_ + 32 + lq * 8]);
    // V'^T A-frags for PV (k=16): A[m = e][k = d0 + half*16 + lq*4 + j]
    short4v vA[4][2];
#pragma unroll
    for (int ec = 0; ec < 4; ++ec) {
      vA[ec][0] = ld4(&Vp[(size_t)(ec * 16 + lm) * T_ + d0 + lq * 4]);
      vA[ec][1] = ld4(&Vp[(size_t)(ec * 16 + lm) * T_ + d0 + 16 + lq * 4]);
    }

#pragma unroll
    for (int tt = 0; tt < 2; ++tt) {
      // S tiles: c0 -> d in [d0,d0+16), c1 -> [d0+16,d0+32); C rows = d, cols = t
      f32x4 c0 = MFMA16(k00, qf[tt][0], zero);
      c0 = MFMA16(k01, qf[tt][1], c0);
      f32x4 c1 = MFMA16(k10, qf[tt][0], zero);
      c1 = MFMA16(k11, qf[tt][1], c1);
      // E = exp2(S') packed bf16: C-layout row=lq*4+r == B-layout k=lq*4+j
      uint32 b00 = pk2(EXP2(c0[0]), EXP2(c0[1]));
      uint32 b01 = pk2(EXP2(c0[2]), EXP2(c0[3]));
      uint32 b10 = pk2(EXP2(c1[0]), EXP2(c1[1]));
      uint32 b11 = pk2(EXP2(c1[2]), EXP2(c1[3]));
      const short4v eB0 = __builtin_bit_cast(short4v, make_uint2(b00, b01));
      const short4v eB1 = __builtin_bit_cast(short4v, make_uint2(b10, b11));
#pragma unroll
      for (int ec = 0; ec < 4; ++ec) {
        acc[tt][ec] = pv_mfma(vA[ec][0], eB0, acc[tt][ec]);
        acc[tt][ec] = pv_mfma(vA[ec][1], eB1, acc[tt][ec]);
      }
    }
  }

  // epilogue: o_ws in (b,t,h,e) fp32; lane holds O^T[e=ec*16+lq*4+r][t=tt*16+lm]
#pragma unroll
  for (int tt = 0; tt < 2; ++tt) {
    const int t = t0 + tt * 16 + lm;
#pragma unroll
    for (int ec = 0; ec < 4; ++ec) {
      float* op = &o_ws[((size_t)(b * T_ + t) * H_ + h) * E_ + ec * 16 + lq * 4];
#pragma unroll
      for (int r = 0; r < 4; ++r) op[r] = acc[tt][ec][r];
    }
  }
}

// ---- unify: out[row, j] = sum_c o_ws[row, c] * Wu[c, j] + bu[j]
__global__ __launch_bounds__(256) void unify_kernel(
    const float* __restrict__ o_ws, const float* __restrict__ Wu,
    const float* __restrict__ bu, float* __restrict__ out) {
  constexpr int RT = 16;
  __shared__ float xs[RT][H_ * E_];
  const int row0 = blockIdx.x * RT;
  const int tid = threadIdx.x;
  for (int idx = tid; idx < RT * 128; idx += 256) {
    const int r = idx >> 7, c4 = idx & 127;
    *(float4*)&xs[r][c4 * 4] = *(const float4*)&o_ws[(size_t)(row0 + r) * 512 + c4 * 4];
  }
  __syncthreads();
  const int j = tid & 63;
  const int rg = tid >> 6;
  float acc[4] = {0.f, 0.f, 0.f, 0.f};
  for (int c = 0; c < 512; ++c) {
    const float w = Wu[c * 64 + j];
#pragma unroll
    for (int r = 0; r < 4; ++r) acc[r] += xs[rg * 4 + r][c] * w;
  }
  const float bias = bu[j];
#pragma unroll
  for (int r = 0; r < 4; ++r)
    out[(size_t)(row0 + rg * 4 + r) * 64 + j] = acc[r] + bias;
}

extern "C" void kernel_launch(void* const* d_in, const int* in_sizes, int n_in,
                              void* d_out, int out_size, void* d_ws, size_t ws_size,
                              hipStream_t stream) {
  const float* values  = (const float*)d_in[0];
  const float* keys    = (const float*)d_in[1];
  const float* queries = (const float*)d_in[2];
  const float* Wv      = (const float*)d_in[3];
  const float* Wk      = (const float*)d_in[4];
  const float* Wq      = (const float*)d_in[5];
  const float* Wu      = (const float*)d_in[6];
  const float* bu      = (const float*)d_in[7];
  float* out = (float*)d_out;

  const size_t NQ = (size_t)BH_ * T_ * E_;  // 4.19M elements
  unsigned short* q_bf  = (unsigned short*)d_ws;
  unsigned short* k_bf  = q_bf + NQ;
  unsigned short* v_bf  = k_bf + NQ;
  unsigned short* vt_bf = v_bf + NQ;
  float* o_ws   = (float*)(vt_bf + NQ);
  float* s_part = o_ws + NQ;  // SZ_ * BH_ * T_ floats

  proj_kernel<<<dim3(B_ * T_ / 8, 3), 512, 0, stream>>>(
      queries, keys, values, Wq, Wk, Wv, q_bf, k_bf, v_bf);
  stats_kernel<<<dim3(T_ / 256, BH_, SZ_), 256, 0, stream>>>(k_bf, q_bf, s_part);
  scale_kernel<<<dim3(T_ / 64, BH_), 256, 0, stream>>>(v_bf, s_part, vt_bf);
  apply_kernel<<<dim3(T_ / 128, BH_), 256, 0, stream>>>(k_bf, q_bf, vt_bf, o_ws);
  unify_kernel<<<B_ * T_ / 16, 256, 0, stream>>>(o_ws, Wu, bu, out);
}

// Round 5
// 390.728 us; speedup vs baseline: 1.0274x; 1.0027x over previous
//
#include <hip/hip_runtime.h>

// ---------------------------------------------------------------------------
// Column-softmax self-attention, bf16 MFMA pipeline, zero-LDS attention core.
//   S'[d,t] = k_d . q_t * (log2e/8)   (scale folded into Q projection)
//   P[d,t]  = exp2(S')/s_d,  s_d = sum_t exp2(S'[d,t])   (no max: |S| small)
//   O^T[e,t] = sum_d V'^T[e,d] * exp2(S'[d,t]),  V'[d,e] = v[d,e]/s_d
// Layout trick (apply): C/D layout of 16x16 MFMA (row=lq*4+r, col=lm) IS the
// B-operand layout of v_mfma_f32_16x16x16_bf16 (k=lq*4+j, n=lm). exp2(S)
// fragments feed PV MFMAs directly; A = V'^T from Vt16[e][d]. No LDS/shuffles.
// R5: distance-2 register prefetch + XCD-affine block swizzle (bh <-> XCD
// affinity shared by stats & apply) + v_cvt_pk_bf16_f32 packing.
// ---------------------------------------------------------------------------

typedef __attribute__((ext_vector_type(8))) __bf16 bf16x8;
typedef __attribute__((ext_vector_type(2))) __bf16 bf16x2;
typedef __attribute__((ext_vector_type(8))) unsigned short ushort8;
typedef __attribute__((ext_vector_type(4))) unsigned short ushort4v;
typedef __attribute__((ext_vector_type(4))) short short4v;
typedef __attribute__((ext_vector_type(4))) float f32x4;
typedef unsigned int uint32;

constexpr int B_ = 4;
constexpr int T_ = 2048;
constexpr int H_ = 8;
constexpr int E_ = 64;
constexpr int BH_ = B_ * H_;
constexpr int SZ_ = 8;  // stats t-split factor
constexpr float QSCALE_ = 0.125f * 1.4426950408889634f;  // 1/sqrt(64) * log2(e)

__device__ inline uint32 f2bf1(float f) {  // fp32 -> bf16 bits, RNE
  uint32 u = __builtin_bit_cast(uint32, f);
  return (u + 0x7fffu + ((u >> 16) & 1u)) >> 16;
}
__device__ inline uint32 pk2(float a, float b) {  // packed bf16 {lo=a, hi=b}
#if __has_builtin(__builtin_amdgcn_cvt_pk_bf16_f32)
  return __builtin_bit_cast(uint32, __builtin_amdgcn_cvt_pk_bf16_f32(a, b));
#else
  return f2bf1(a) | (f2bf1(b) << 16);
#endif
}
__device__ inline float bf2f(uint32 bits) {
  return __builtin_bit_cast(float, bits << 16);
}
__device__ inline bf16x8 ld8(const unsigned short* p) {
  return __builtin_bit_cast(bf16x8, *(const ushort8*)p);
}
__device__ inline short4v ld4(const unsigned short* p) {
  return __builtin_bit_cast(short4v, *(const ushort4v*)p);
}
#define MFMA16(a, b, c) __builtin_amdgcn_mfma_f32_16x16x32_bf16(a, b, c, 0, 0, 0)
#define EXP2(x) __builtin_amdgcn_exp2f(x)

// k=16 bf16 MFMA (PV step): A,B are 4 bf16 (2 VGPRs) each
__device__ inline f32x4 pv_mfma(short4v a, short4v b, f32x4 c) {
#if __has_builtin(__builtin_amdgcn_mfma_f32_16x16x16bf16_1k)
  return __builtin_amdgcn_mfma_f32_16x16x16bf16_1k(a, b, c, 0, 0, 0);
#else
  asm("v_mfma_f32_16x16x16_bf16 %0, %1, %2, %0" : "+v"(c) : "v"(a), "v"(b));
  return c;
#endif
}

// ---- fused projections: grid.y = 0(Q) / 1(K) / 2(V); output bf16 (b,h,t,e)
__global__ __launch_bounds__(512) void proj_kernel(
    const float* __restrict__ Xq, const float* __restrict__ Xk,
    const float* __restrict__ Xv, const float* __restrict__ Wq,
    const float* __restrict__ Wk, const float* __restrict__ Wv,
    unsigned short* __restrict__ Yq, unsigned short* __restrict__ Yk,
    unsigned short* __restrict__ Yv) {
  constexpr int RT = 8;
  __shared__ float xs[RT][E_];
  const int z = blockIdx.y;
  const float* X = (z == 0) ? Xq : (z == 1) ? Xk : Xv;
  const float* W = (z == 0) ? Wq : (z == 1) ? Wk : Wv;
  unsigned short* Y = (z == 0) ? Yq : (z == 1) ? Yk : Yv;
  const float scale = (z == 0) ? QSCALE_ : 1.0f;
  const int row0 = blockIdx.x * RT;  // row = b*T + t
  const int tid = threadIdx.x;
  {
    const int r = tid >> 6, c = tid & 63;
    xs[r][c] = X[(row0 + r) * E_ + c];
  }
  __syncthreads();
  const int j = tid;
  const int h = j >> 6, e = j & 63;
  float acc[RT];
#pragma unroll
  for (int r = 0; r < RT; ++r) acc[r] = 0.f;
  for (int c = 0; c < E_; ++c) {
    const float w = W[c * (H_ * E_) + j];
#pragma unroll
    for (int r = 0; r < RT; ++r) acc[r] += xs[r][c] * w;
  }
#pragma unroll
  for (int r = 0; r < RT; ++r) {
    const int row = row0 + r;
    const int b = row >> 11, t = row & (T_ - 1);
    Y[(((size_t)(b * H_ + h) * T_ + t) << 6) + e] =
        (unsigned short)f2bf1(acc[r] * scale);
  }
}

// ---- pass A: s_part[z][bh][d] = sum_{t in slice} exp2(S'[d,t])
// 1D grid, XCD-affine: g&7 selects XCD; bh = (g&7) + 8*(slot>>6).
__global__ __launch_bounds__(256, 4) void stats_kernel(
    const unsigned short* __restrict__ K16, const unsigned short* __restrict__ Q16,
    float* __restrict__ s_part) {
  const int g = blockIdx.x;          // 0..2047
  const int x = g & 7, s = g >> 3;   // s: 0..255
  const int bh = x + 8 * (s >> 6);
  const int rem = s & 63;
  const int zi = rem >> 3;           // 0..7 (t-slice)
  const int dblk = rem & 7;          // 0..7
  const int tid = threadIdx.x;
  const int w = tid >> 6, lane = tid & 63;
  const int lm = lane & 15, lq = lane >> 4;
  const int d0 = dblk * 256 + w * 64;
  const int tz0 = zi * (T_ / SZ_);
  const unsigned short* Kp = K16 + (size_t)bh * T_ * E_;
  const unsigned short* Qp = Q16 + (size_t)bh * T_ * E_;

  bf16x8 kf[4][2];  // loop-invariant K fragments (64 d rows)
#pragma unroll
  for (int dt = 0; dt < 4; ++dt) {
    kf[dt][0] = ld8(&Kp[(size_t)(d0 + dt * 16 + lm) * E_ + lq * 8]);
    kf[dt][1] = ld8(&Kp[(size_t)(d0 + dt * 16 + lm) * E_ + 32 + lq * 8]);
  }
  f32x4 sacc[4];
#pragma unroll
  for (int dt = 0; dt < 4; ++dt) sacc[dt] = (f32x4){0.f, 0.f, 0.f, 0.f};
  const f32x4 zero = {0.f, 0.f, 0.f, 0.f};

  // distance-2 register-prefetched Q sweep (16-row tiles, 16 iters)
  bf16x8 q0l = ld8(&Qp[(size_t)(tz0 + lm) * E_ + lq * 8]);
  bf16x8 q0h = ld8(&Qp[(size_t)(tz0 + lm) * E_ + 32 + lq * 8]);
  bf16x8 q1l = ld8(&Qp[(size_t)(tz0 + 16 + lm) * E_ + lq * 8]);
  bf16x8 q1h = ld8(&Qp[(size_t)(tz0 + 16 + lm) * E_ + 32 + lq * 8]);
#define STATS_STEP(QL, QH)                              \
  {                                                     \
    _Pragma("unroll") for (int dt = 0; dt < 4; ++dt) {  \
      f32x4 c = MFMA16(kf[dt][0], (QL), zero);          \
      c = MFMA16(kf[dt][1], (QH), c);                   \
      _Pragma("unroll") for (int r = 0; r < 4; ++r)     \
          sacc[dt][r] += EXP2(c[r]);                    \
    }                                                   \
  }
  for (int t0 = tz0; t0 < tz0 + 256; t0 += 32) {
    const int tp0 = tz0 + ((t0 + 32 - tz0) & 255);
    const int tp1 = tz0 + ((t0 + 48 - tz0) & 255);
    STATS_STEP(q0l, q0h);
    q0l = ld8(&Qp[(size_t)(tp0 + lm) * E_ + lq * 8]);
    q0h = ld8(&Qp[(size_t)(tp0 + lm) * E_ + 32 + lq * 8]);
    STATS_STEP(q1l, q1h);
    q1l = ld8(&Qp[(size_t)(tp1 + lm) * E_ + lq * 8]);
    q1h = ld8(&Qp[(size_t)(tp1 + lm) * E_ + 32 + lq * 8]);
  }
#undef STATS_STEP
  // reduce over the 16 column-lanes (t within tile)
#pragma unroll
  for (int m = 1; m < 16; m <<= 1) {
#pragma unroll
    for (int dt = 0; dt < 4; ++dt)
#pragma unroll
      for (int r = 0; r < 4; ++r)
        sacc[dt][r] += __shfl_xor(sacc[dt][r], m);
  }
  if (lm == 0) {
#pragma unroll
    for (int dt = 0; dt < 4; ++dt)
#pragma unroll
      for (int r = 0; r < 4; ++r)
        s_part[((size_t)zi * BH_ + bh) * T_ + d0 + dt * 16 + lq * 4 + r] =
            sacc[dt][r];
  }
}

// ---- scale+transpose: Vt[bh][e][d] = v_bf[bh][d][e] / s_d  (bf16)
__global__ __launch_bounds__(256) void scale_kernel(
    const unsigned short* __restrict__ V16, const float* __restrict__ s_part,
    unsigned short* __restrict__ Vt16) {
  __shared__ float ts[64][68];
  __shared__ float sinv_s[64];
  const int bh = blockIdx.y;
  const int d0 = blockIdx.x * 64;
  const unsigned short* Vp = V16 + (size_t)bh * T_ * E_;
  const int tid = threadIdx.x;
  if (tid < 64) {
    float s = 0.f;
#pragma unroll
    for (int z = 0; z < SZ_; ++z)
      s += s_part[((size_t)z * BH_ + bh) * T_ + d0 + tid];
    sinv_s[tid] = 1.0f / s;
  }
  __syncthreads();
  for (int idx = tid; idx < 64 * 8; idx += 256) {
    const int r = idx >> 3, c8 = idx & 7;
    const ushort8 v8 = *(const ushort8*)&Vp[(size_t)(d0 + r) * E_ + c8 * 8];
    const float is = sinv_s[r];
#pragma unroll
    for (int k = 0; k < 8; ++k) ts[r][c8 * 8 + k] = bf2f(v8[k]) * is;
  }
  __syncthreads();
  for (int idx = tid; idx < 64 * 16; idx += 256) {
    const int e = idx >> 4, d4 = idx & 15;
    uint2 o;
    o.x = pk2(ts[d4 * 4 + 0][e], ts[d4 * 4 + 1][e]);
    o.y = pk2(ts[d4 * 4 + 2][e], ts[d4 * 4 + 3][e]);
    *(uint2*)&Vt16[((size_t)bh * E_ + e) * T_ + d0 + d4 * 4] = o;
  }
}

// ---- apply: per-chunk loads (K rows d0..d0+32, V'^T cols d0..d0+32)
__device__ inline void ld_stage(const unsigned short* __restrict__ Kp,
                                const unsigned short* __restrict__ Vp,
                                int d0, int lm, int lq,
                                bf16x8 K[4], short4v V[8]) {
  K[0] = ld8(&Kp[(size_t)(d0 + lm) * E_ + lq * 8]);
  K[1] = ld8(&Kp[(size_t)(d0 + lm) * E_ + 32 + lq * 8]);
  K[2] = ld8(&Kp[(size_t)(d0 + 16 + lm) * E_ + lq * 8]);
  K[3] = ld8(&Kp[(size_t)(d0 + 16 + lm) * E_ + 32 + lq * 8]);
#pragma unroll
  for (int ec = 0; ec < 4; ++ec) {
    V[ec * 2]     = ld4(&Vp[(size_t)(ec * 16 + lm) * T_ + d0 + lq * 4]);
    V[ec * 2 + 1] = ld4(&Vp[(size_t)(ec * 16 + lm) * T_ + d0 + 16 + lq * 4]);
  }
}

__device__ inline void compute_chunk(const bf16x8 K[4], const short4v V[8],
                                     const bf16x8 qf[2][2], f32x4 acc[2][4]) {
  const f32x4 zero = {0.f, 0.f, 0.f, 0.f};
#pragma unroll
  for (int tt = 0; tt < 2; ++tt) {
    // S tiles: c0 -> d in [d0,d0+16), c1 -> [d0+16,d0+32); C rows = d, cols = t
    f32x4 c0 = MFMA16(K[0], qf[tt][0], zero);
    c0 = MFMA16(K[1], qf[tt][1], c0);
    f32x4 c1 = MFMA16(K[2], qf[tt][0], zero);
    c1 = MFMA16(K[3], qf[tt][1], c1);
    // E = exp2(S') packed bf16: C-layout row=lq*4+r == B-layout k=lq*4+j
    const uint32 b00 = pk2(EXP2(c0[0]), EXP2(c0[1]));
    const uint32 b01 = pk2(EXP2(c0[2]), EXP2(c0[3]));
    const uint32 b10 = pk2(EXP2(c1[0]), EXP2(c1[1]));
    const uint32 b11 = pk2(EXP2(c1[2]), EXP2(c1[3]));
    const short4v eB0 = __builtin_bit_cast(short4v, make_uint2(b00, b01));
    const short4v eB1 = __builtin_bit_cast(short4v, make_uint2(b10, b11));
#pragma unroll
    for (int ec = 0; ec < 4; ++ec) {
      acc[tt][ec] = pv_mfma(V[ec * 2], eB0, acc[tt][ec]);
      acc[tt][ec] = pv_mfma(V[ec * 2 + 1], eB1, acc[tt][ec]);
    }
  }
}

// ---- pass B: O^T[e,t] = sum_d V'^T[e,d] exp2(S'[d,t]); wave: 32 t x 64 e
// 1D grid, XCD-affine decode matching stats (same bh set per XCD).
__global__ __launch_bounds__(256, 2) void apply_kernel(
    const unsigned short* __restrict__ K16, const unsigned short* __restrict__ Q16,
    const unsigned short* __restrict__ Vt16, float* __restrict__ o_ws) {
  const int g = blockIdx.x;          // 0..511
  const int x = g & 7, s = g >> 3;   // s: 0..63
  const int bh = x + 8 * (s >> 4);
  const int tblk = s & 15;
  const int b = bh >> 3, h = bh & 7;
  const int tid = threadIdx.x;
  const int w = tid >> 6, lane = tid & 63;
  const int lm = lane & 15, lq = lane >> 4;
  const int t0 = tblk * 128 + w * 32;
  const unsigned short* Kp = K16 + (size_t)bh * T_ * E_;
  const unsigned short* Qp = Q16 + (size_t)bh * T_ * E_;
  const unsigned short* Vp = Vt16 + (size_t)bh * E_ * T_;

  // loop-invariant Q fragments (B operand of S-MFMA: k=e, n=t)
  bf16x8 qf[2][2];
#pragma unroll
  for (int tt = 0; tt < 2; ++tt) {
    qf[tt][0] = ld8(&Qp[(size_t)(t0 + tt * 16 + lm) * E_ + lq * 8]);
    qf[tt][1] = ld8(&Qp[(size_t)(t0 + tt * 16 + lm) * E_ + 32 + lq * 8]);
  }
  f32x4 acc[2][4];  // O^T[e = ec*16 + lq*4 + r][t = t0 + tt*16 + lm]
#pragma unroll
  for (int tt = 0; tt < 2; ++tt)
#pragma unroll
    for (int ec = 0; ec < 4; ++ec) acc[tt][ec] = (f32x4){0.f, 0.f, 0.f, 0.f};

  // distance-2 software pipeline over 32-d chunks
  bf16x8 K0[4], K1[4];
  short4v V0[8], V1[8];
  ld_stage(Kp, Vp, 0, lm, lq, K0, V0);
  ld_stage(Kp, Vp, 32, lm, lq, K1, V1);
  for (int d0 = 0; d0 < T_; d0 += 64) {
    compute_chunk(K0, V0, qf, acc);
    ld_stage(Kp, Vp, (d0 + 64) & (T_ - 1), lm, lq, K0, V0);
    compute_chunk(K1, V1, qf, acc);
    ld_stage(Kp, Vp, (d0 + 96) & (T_ - 1), lm, lq, K1, V1);
  }

  // epilogue: o_ws in (b,t,h,e) fp32; lane holds O^T[e=ec*16+lq*4+r][t=tt*16+lm]
#pragma unroll
  for (int tt = 0; tt < 2; ++tt) {
    const int t = t0 + tt * 16 + lm;
#pragma unroll
    for (int ec = 0; ec < 4; ++ec) {
      float* op = &o_ws[((size_t)(b * T_ + t) * H_ + h) * E_ + ec * 16 + lq * 4];
      *(float4*)op = make_float4(acc[tt][ec][0], acc[tt][ec][1],
                                 acc[tt][ec][2], acc[tt][ec][3]);
    }
  }
}

// ---- unify: out[row, j] = sum_c o_ws[row, c] * Wu[c, j] + bu[j]
__global__ __launch_bounds__(256) void unify_kernel(
    const float* __restrict__ o_ws, const float* __restrict__ Wu,
    const float* __restrict__ bu, float* __restrict__ out) {
  constexpr int RT = 16;
  __shared__ float xs[RT][H_ * E_];
  const int row0 = blockIdx.x * RT;
  const int tid = threadIdx.x;
  for (int idx = tid; idx < RT * 128; idx += 256) {
    const int r = idx >> 7, c4 = idx & 127;
    *(float4*)&xs[r][c4 * 4] = *(const float4*)&o_ws[(size_t)(row0 + r) * 512 + c4 * 4];
  }
  __syncthreads();
  const int j = tid & 63;
  const int rg = tid >> 6;
  float acc[4] = {0.f, 0.f, 0.f, 0.f};
  for (int c = 0; c < 512; ++c) {
    const float w = Wu[c * 64 + j];
#pragma unroll
    for (int r = 0; r < 4; ++r) acc[r] += xs[rg * 4 + r][c] * w;
  }
  const float bias = bu[j];
#pragma unroll
  for (int r = 0; r < 4; ++r)
    out[(size_t)(row0 + rg * 4 + r) * 64 + j] = acc[r] + bias;
}

extern "C" void kernel_launch(void* const* d_in, const int* in_sizes, int n_in,
                              void* d_out, int out_size, void* d_ws, size_t ws_size,
                              hipStream_t stream) {
  const float* values  = (const float*)d_in[0];
  const float* keys    = (const float*)d_in[1];
  const float* queries = (const float*)d_in[2];
  const float* Wv      = (const float*)d_in[3];
  const float* Wk      = (const float*)d_in[4];
  const float* Wq      = (const float*)d_in[5];
  const float* Wu      = (const float*)d_in[6];
  const float* bu      = (const float*)d_in[7];
  float* out = (float*)d_out;

  const size_t NQ = (size_t)BH_ * T_ * E_;  // 4.19M elements
  unsigned short* q_bf  = (unsigned short*)d_ws;
  unsigned short* k_bf  = q_bf + NQ;
  unsigned short* v_bf  = k_bf + NQ;
  unsigned short* vt_bf = v_bf + NQ;
  float* o_ws   = (float*)(vt_bf + NQ);
  float* s_part = o_ws + NQ;  // SZ_ * BH_ * T_ floats

  proj_kernel<<<dim3(B_ * T_ / 8, 3), 512, 0, stream>>>(
      queries, keys, values, Wq, Wk, Wv, q_bf, k_bf, v_bf);
  stats_kernel<<<T_ / 256 * BH_ * SZ_, 256, 0, stream>>>(k_bf, q_bf, s_part);
  scale_kernel<<<dim3(T_ / 64, BH_), 256, 0, stream>>>(v_bf, s_part, vt_bf);
  apply_kernel<<<T_ / 128 * BH_, 256, 0, stream>>>(k_bf, q_bf, vt_bf, o_ws);
  unify_kernel<<<B_ * T_ / 16, 256, 0, stream>>>(o_ws, Wu, bu, out);
}

// Round 6
// 289.618 us; speedup vs baseline: 1.3861x; 1.3491x over previous
//
#include <hip/hip_runtime.h>

// ---------------------------------------------------------------------------
// Column-softmax self-attention, bf16 MFMA pipeline.
//   S'[d,t] = k_d . q_t * (log2e/8)   (scale folded into Q projection)
//   P[d,t]  = exp2(S')/s_d,  s_d = sum_t exp2(S'[d,t])   (no max: |S| small)
//   O^T[e,t] = sum_d V'^T[e,d] * exp2(S'[d,t]),  V'[d,e] = v[d,e]/s_d
// apply (R6): m97-style LDS double-buffer via global_load_lds DMA (no VGPR
// staging -> scheduler can't serialize loads), 4x traffic dedup across the
// block's waves, d-split x2 for 4 blocks/CU. exp2(S) C-fragments feed
// v_mfma_f32_16x16x16_bf16 directly as B operands (C-layout == B-layout).
// ---------------------------------------------------------------------------

typedef __attribute__((ext_vector_type(8))) __bf16 bf16x8;
typedef __attribute__((ext_vector_type(8))) unsigned short ushort8;
typedef __attribute__((ext_vector_type(4))) unsigned short ushort4v;
typedef __attribute__((ext_vector_type(4))) short short4v;
typedef __attribute__((ext_vector_type(4))) float f32x4;
typedef unsigned int uint32;

constexpr int B_ = 4;
constexpr int T_ = 2048;
constexpr int H_ = 8;
constexpr int E_ = 64;
constexpr int BH_ = B_ * H_;
constexpr int SZ_ = 8;   // stats t-split factor
constexpr int NP_ = 2;   // apply d-split factor
constexpr float QSCALE_ = 0.125f * 1.4426950408889634f;  // 1/sqrt(64) * log2(e)

__device__ inline uint32 f2bf1(float f) {  // fp32 -> bf16 bits, RNE
  uint32 u = __builtin_bit_cast(uint32, f);
  return (u + 0x7fffu + ((u >> 16) & 1u)) >> 16;
}
__device__ inline uint32 pk2(float a, float b) {  // packed bf16 {lo=a, hi=b}
#if __has_builtin(__builtin_amdgcn_cvt_pk_bf16_f32)
  return __builtin_bit_cast(uint32, __builtin_amdgcn_cvt_pk_bf16_f32(a, b));
#else
  return f2bf1(a) | (f2bf1(b) << 16);
#endif
}
__device__ inline float bf2f(uint32 bits) {
  return __builtin_bit_cast(float, bits << 16);
}
__device__ inline bf16x8 ld8(const unsigned short* p) {
  return __builtin_bit_cast(bf16x8, *(const ushort8*)p);
}
__device__ inline short4v ld4(const unsigned short* p) {
  return __builtin_bit_cast(short4v, *(const ushort4v*)p);
}
#define MFMA16(a, b, c) __builtin_amdgcn_mfma_f32_16x16x32_bf16(a, b, c, 0, 0, 0)
#define EXP2(x) __builtin_amdgcn_exp2f(x)

// k=16 bf16 MFMA (PV step): A,B are 4 bf16 (2 VGPRs) each
__device__ inline f32x4 pv_mfma(short4v a, short4v b, f32x4 c) {
#if __has_builtin(__builtin_amdgcn_mfma_f32_16x16x16bf16_1k)
  return __builtin_amdgcn_mfma_f32_16x16x16bf16_1k(a, b, c, 0, 0, 0);
#else
  asm("v_mfma_f32_16x16x16_bf16 %0, %1, %2, %0" : "+v"(c) : "v"(a), "v"(b));
  return c;
#endif
}

// async 16B/lane global->LDS DMA: lds base must be wave-uniform; lane i's 16B
// lands at base + i*16.
__device__ inline void dma16(const unsigned short* g, unsigned short* l) {
  __builtin_amdgcn_global_load_lds(
      (const __attribute__((address_space(1))) void*)g,
      (__attribute__((address_space(3))) void*)l, 16, 0, 0);
}

// ---- fused projections: grid.y = 0(Q) / 1(K) / 2(V); output bf16 (b,h,t,e)
__global__ __launch_bounds__(512) void proj_kernel(
    const float* __restrict__ Xq, const float* __restrict__ Xk,
    const float* __restrict__ Xv, const float* __restrict__ Wq,
    const float* __restrict__ Wk, const float* __restrict__ Wv,
    unsigned short* __restrict__ Yq, unsigned short* __restrict__ Yk,
    unsigned short* __restrict__ Yv) {
  constexpr int RT = 8;
  __shared__ float xs[RT][E_];
  const int z = blockIdx.y;
  const float* X = (z == 0) ? Xq : (z == 1) ? Xk : Xv;
  const float* W = (z == 0) ? Wq : (z == 1) ? Wk : Wv;
  unsigned short* Y = (z == 0) ? Yq : (z == 1) ? Yk : Yv;
  const float scale = (z == 0) ? QSCALE_ : 1.0f;
  const int row0 = blockIdx.x * RT;  // row = b*T + t
  const int tid = threadIdx.x;
  {
    const int r = tid >> 6, c = tid & 63;
    xs[r][c] = X[(row0 + r) * E_ + c];
  }
  __syncthreads();
  const int j = tid;
  const int h = j >> 6, e = j & 63;
  float acc[RT];
#pragma unroll
  for (int r = 0; r < RT; ++r) acc[r] = 0.f;
  for (int c = 0; c < E_; ++c) {
    const float w = W[c * (H_ * E_) + j];
#pragma unroll
    for (int r = 0; r < RT; ++r) acc[r] += xs[r][c] * w;
  }
#pragma unroll
  for (int r = 0; r < RT; ++r) {
    const int row = row0 + r;
    const int b = row >> 11, t = row & (T_ - 1);
    Y[(((size_t)(b * H_ + h) * T_ + t) << 6) + e] =
        (unsigned short)f2bf1(acc[r] * scale);
  }
}

// ---- pass A: s_part[z][bh][d] = sum_{t in slice} exp2(S'[d,t])
// 1D grid, XCD-affine: g&7 selects XCD; bh = (g&7) + 8*(slot>>6).
__global__ __launch_bounds__(256, 4) void stats_kernel(
    const unsigned short* __restrict__ K16, const unsigned short* __restrict__ Q16,
    float* __restrict__ s_part) {
  const int g = blockIdx.x;          // 0..2047
  const int x = g & 7, s = g >> 3;   // s: 0..255
  const int bh = x + 8 * (s >> 6);
  const int rem = s & 63;
  const int zi = rem >> 3;           // 0..7 (t-slice)
  const int dblk = rem & 7;          // 0..7
  const int tid = threadIdx.x;
  const int w = tid >> 6, lane = tid & 63;
  const int lm = lane & 15, lq = lane >> 4;
  const int d0 = dblk * 256 + w * 64;
  const int tz0 = zi * (T_ / SZ_);
  const unsigned short* Kp = K16 + (size_t)bh * T_ * E_;
  const unsigned short* Qp = Q16 + (size_t)bh * T_ * E_;

  bf16x8 kf[4][2];  // loop-invariant K fragments (64 d rows)
#pragma unroll
  for (int dt = 0; dt < 4; ++dt) {
    kf[dt][0] = ld8(&Kp[(size_t)(d0 + dt * 16 + lm) * E_ + lq * 8]);
    kf[dt][1] = ld8(&Kp[(size_t)(d0 + dt * 16 + lm) * E_ + 32 + lq * 8]);
  }
  f32x4 sacc[4];
#pragma unroll
  for (int dt = 0; dt < 4; ++dt) sacc[dt] = (f32x4){0.f, 0.f, 0.f, 0.f};
  const f32x4 zero = {0.f, 0.f, 0.f, 0.f};

  for (int t0 = tz0; t0 < tz0 + 256; t0 += 16) {
    const bf16x8 ql = ld8(&Qp[(size_t)(t0 + lm) * E_ + lq * 8]);
    const bf16x8 qh = ld8(&Qp[(size_t)(t0 + lm) * E_ + 32 + lq * 8]);
#pragma unroll
    for (int dt = 0; dt < 4; ++dt) {
      f32x4 c = MFMA16(kf[dt][0], ql, zero);
      c = MFMA16(kf[dt][1], qh, c);
#pragma unroll
      for (int r = 0; r < 4; ++r) sacc[dt][r] += EXP2(c[r]);
    }
  }
  // reduce over the 16 column-lanes (t within tile)
#pragma unroll
  for (int m = 1; m < 16; m <<= 1) {
#pragma unroll
    for (int dt = 0; dt < 4; ++dt)
#pragma unroll
      for (int r = 0; r < 4; ++r)
        sacc[dt][r] += __shfl_xor(sacc[dt][r], m);
  }
  if (lm == 0) {
#pragma unroll
    for (int dt = 0; dt < 4; ++dt)
#pragma unroll
      for (int r = 0; r < 4; ++r)
        s_part[((size_t)zi * BH_ + bh) * T_ + d0 + dt * 16 + lq * 4 + r] =
            sacc[dt][r];
  }
}

// ---- scale+transpose: Vt[bh][e][d] = v_bf[bh][d][e] / s_d  (bf16)
__global__ __launch_bounds__(256) void scale_kernel(
    const unsigned short* __restrict__ V16, const float* __restrict__ s_part,
    unsigned short* __restrict__ Vt16) {
  __shared__ float ts[64][68];
  __shared__ float sinv_s[64];
  const int bh = blockIdx.y;
  const int d0 = blockIdx.x * 64;
  const unsigned short* Vp = V16 + (size_t)bh * T_ * E_;
  const int tid = threadIdx.x;
  if (tid < 64) {
    float s = 0.f;
#pragma unroll
    for (int z = 0; z < SZ_; ++z)
      s += s_part[((size_t)z * BH_ + bh) * T_ + d0 + tid];
    sinv_s[tid] = 1.0f / s;
  }
  __syncthreads();
  for (int idx = tid; idx < 64 * 8; idx += 256) {
    const int r = idx >> 3, c8 = idx & 7;
    const ushort8 v8 = *(const ushort8*)&Vp[(size_t)(d0 + r) * E_ + c8 * 8];
    const float is = sinv_s[r];
#pragma unroll
    for (int k = 0; k < 8; ++k) ts[r][c8 * 8 + k] = bf2f(v8[k]) * is;
  }
  __syncthreads();
  for (int idx = tid; idx < 64 * 16; idx += 256) {
    const int e = idx >> 4, d4 = idx & 15;
    uint2 o;
    o.x = pk2(ts[d4 * 4 + 0][e], ts[d4 * 4 + 1][e]);
    o.y = pk2(ts[d4 * 4 + 2][e], ts[d4 * 4 + 3][e]);
    *(uint2*)&Vt16[((size_t)bh * E_ + e) * T_ + d0 + d4 * 4] = o;
  }
}

// ---- pass B: O^T[e,t] = sum_{d in half} V'^T[e,d] exp2(S'[d,t])
// Block: 128 t (4 waves x 32t x 64e), d-range 1024 (32 chunks of 32).
// K/Vt chunks staged to LDS via async DMA, double-buffered (m97 structure).
// K LDS rows carry an XOR-on-d segment permutation (conflict mitigation).
__global__ __launch_bounds__(256, 4) void apply_kernel(
    const unsigned short* __restrict__ K16, const unsigned short* __restrict__ Q16,
    const unsigned short* __restrict__ Vt16, float* __restrict__ o_part) {
  __shared__ __align__(16) unsigned short K_s[2][32 * 64];  // [d-local][e] perm'd
  __shared__ __align__(16) unsigned short V_s[2][64 * 32];  // [e][d-local]
  const int g = blockIdx.x;            // 0..1023
  const int xcd = g & 7, slot = g >> 3;  // slot 0..127
  const int bh = xcd + 8 * (slot >> 5);  // 4 bh per XCD -> K+Vt fit in 4MB L2
  const int rem = slot & 31;
  const int np = rem >> 4;               // d-half (0/1)
  const int tblk = rem & 15;
  const int b = bh >> 3, h = bh & 7;
  const int tid = threadIdx.x;
  const int w = tid >> 6, lane = tid & 63;
  const int lm = lane & 15, lq = lane >> 4;
  const int t0 = tblk * 128 + w * 32;
  const int dbase = np * (T_ / NP_);
  constexpr int NC = (T_ / NP_) / 32;  // 32 chunks
  const unsigned short* Kp = K16 + (size_t)bh * T_ * E_;
  const unsigned short* Qp = Q16 + (size_t)bh * T_ * E_;
  const unsigned short* Vp = Vt16 + (size_t)bh * E_ * T_;

  // per-lane DMA source addresses (chunk-invariant part)
  const int kr = lane >> 3, kp = lane & 7, ks = kp ^ kr;  // K seg perm: pos p holds seg p^d
  const unsigned short* gK = Kp + (size_t)(w * 8 + kr) * E_ + ks * 8;
  const int ve = w * 16 + (lane >> 2), vseg = lane & 3;
  const unsigned short* gV = Vp + (size_t)ve * T_ + vseg * 8;
  unsigned short* lK0 = &K_s[0][w * 512];
  unsigned short* lK1 = &K_s[1][w * 512];
  unsigned short* lV0 = &V_s[0][w * 512];
  unsigned short* lV1 = &V_s[1][w * 512];

  // loop-invariant Q fragments (B operand of S-MFMA: k=e, n=t)
  bf16x8 qf[2][2];
#pragma unroll
  for (int tt = 0; tt < 2; ++tt) {
    qf[tt][0] = ld8(&Qp[(size_t)(t0 + tt * 16 + lm) * E_ + lq * 8]);
    qf[tt][1] = ld8(&Qp[(size_t)(t0 + tt * 16 + lm) * E_ + 32 + lq * 8]);
  }
  f32x4 acc[2][4];  // O^T[e = ec*16 + lq*4 + r][t = t0 + tt*16 + lm]
#pragma unroll
  for (int tt = 0; tt < 2; ++tt)
#pragma unroll
    for (int ec = 0; ec < 4; ++ec) acc[tt][ec] = (f32x4){0.f, 0.f, 0.f, 0.f};
  const f32x4 zero = {0.f, 0.f, 0.f, 0.f};

  // prime buffer 0
  dma16(gK + (size_t)dbase * E_, lK0);
  dma16(gV + dbase, lV0);
  __syncthreads();

  for (int c = 0; c < NC; ++c) {
    const int cur = c & 1;
    if (c + 1 < NC) {  // DMA next chunk into the other buffer
      const int dn = dbase + (c + 1) * 32;
      dma16(gK + (size_t)dn * E_, cur ? lK0 : lK1);
      dma16(gV + dn, cur ? lV0 : lV1);
    }
    const unsigned short* Kb = K_s[cur];
    const unsigned short* Vb = V_s[cur];
    // K A-frags: row d=half*16+lm, seg position (hi*4+lq)^(lm&7)
    bf16x8 kf[2][2];
#pragma unroll
    for (int half = 0; half < 2; ++half)
#pragma unroll
      for (int hi = 0; hi < 2; ++hi)
        kf[half][hi] =
            ld8(&Kb[(half * 16 + lm) * 64 + (((hi * 4 + lq) ^ (lm & 7)) * 8)]);
    // V A-frags: row e=ec*16+lm, d-local = half*16 + lq*4
    short4v vf[4][2];
#pragma unroll
    for (int ec = 0; ec < 4; ++ec)
#pragma unroll
      for (int half = 0; half < 2; ++half)
        vf[ec][half] = ld4(&Vb[(ec * 16 + lm) * 32 + half * 16 + lq * 4]);

#pragma unroll
    for (int tt = 0; tt < 2; ++tt) {
      // S tiles: c0 -> d-local [0,16), c1 -> [16,32); C rows = d, cols = t
      f32x4 c0 = MFMA16(kf[0][0], qf[tt][0], zero);
      c0 = MFMA16(kf[0][1], qf[tt][1], c0);
      f32x4 c1 = MFMA16(kf[1][0], qf[tt][0], zero);
      c1 = MFMA16(kf[1][1], qf[tt][1], c1);
      // E = exp2(S') packed bf16: C-layout row=lq*4+r == B-layout k=lq*4+j
      const uint32 b00 = pk2(EXP2(c0[0]), EXP2(c0[1]));
      const uint32 b01 = pk2(EXP2(c0[2]), EXP2(c0[3]));
      const uint32 b10 = pk2(EXP2(c1[0]), EXP2(c1[1]));
      const uint32 b11 = pk2(EXP2(c1[2]), EXP2(c1[3]));
      const short4v eB0 = __builtin_bit_cast(short4v, make_uint2(b00, b01));
      const short4v eB1 = __builtin_bit_cast(short4v, make_uint2(b10, b11));
#pragma unroll
      for (int ec = 0; ec < 4; ++ec) {
        acc[tt][ec] = pv_mfma(vf[ec][0], eB0, acc[tt][ec]);
        acc[tt][ec] = pv_mfma(vf[ec][1], eB1, acc[tt][ec]);
      }
    }
    __syncthreads();
  }

  // epilogue: partial O in (b,t,h,e) fp32 at o_part + np*NQ
  float* op_base = o_part + (size_t)np * BH_ * T_ * E_;
#pragma unroll
  for (int tt = 0; tt < 2; ++tt) {
    const int t = t0 + tt * 16 + lm;
#pragma unroll
    for (int ec = 0; ec < 4; ++ec) {
      float* op = &op_base[((size_t)(b * T_ + t) * H_ + h) * E_ + ec * 16 + lq * 4];
      *(float4*)op = make_float4(acc[tt][ec][0], acc[tt][ec][1],
                                 acc[tt][ec][2], acc[tt][ec][3]);
    }
  }
}

// ---- unify: out[row, j] = sum_c (o0+o1)[row, c] * Wu[c, j] + bu[j]
__global__ __launch_bounds__(256) void unify_kernel(
    const float* __restrict__ o0, const float* __restrict__ o1,
    const float* __restrict__ Wu, const float* __restrict__ bu,
    float* __restrict__ out) {
  constexpr int RT = 16;
  __shared__ float xs[RT][H_ * E_];
  const int row0 = blockIdx.x * RT;
  const int tid = threadIdx.x;
  for (int idx = tid; idx < RT * 128; idx += 256) {
    const int r = idx >> 7, c4 = idx & 127;
    const float4 a = *(const float4*)&o0[(size_t)(row0 + r) * 512 + c4 * 4];
    const float4 bv = *(const float4*)&o1[(size_t)(row0 + r) * 512 + c4 * 4];
    xs[r][c4 * 4 + 0] = a.x + bv.x;
    xs[r][c4 * 4 + 1] = a.y + bv.y;
    xs[r][c4 * 4 + 2] = a.z + bv.z;
    xs[r][c4 * 4 + 3] = a.w + bv.w;
  }
  __syncthreads();
  const int j = tid & 63;
  const int rg = tid >> 6;
  float acc[4] = {0.f, 0.f, 0.f, 0.f};
  for (int c = 0; c < 512; ++c) {
    const float w = Wu[c * 64 + j];
#pragma unroll
    for (int r = 0; r < 4; ++r) acc[r] += xs[rg * 4 + r][c] * w;
  }
  const float bias = bu[j];
#pragma unroll
  for (int r = 0; r < 4; ++r)
    out[(size_t)(row0 + rg * 4 + r) * 64 + j] = acc[r] + bias;
}

extern "C" void kernel_launch(void* const* d_in, const int* in_sizes, int n_in,
                              void* d_out, int out_size, void* d_ws, size_t ws_size,
                              hipStream_t stream) {
  const float* values  = (const float*)d_in[0];
  const float* keys    = (const float*)d_in[1];
  const float* queries = (const float*)d_in[2];
  const float* Wv      = (const float*)d_in[3];
  const float* Wk      = (const float*)d_in[4];
  const float* Wq      = (const float*)d_in[5];
  const float* Wu      = (const float*)d_in[6];
  const float* bu      = (const float*)d_in[7];
  float* out = (float*)d_out;

  const size_t NQ = (size_t)BH_ * T_ * E_;  // 4.19M elements
  unsigned short* q_bf  = (unsigned short*)d_ws;
  unsigned short* k_bf  = q_bf + NQ;
  unsigned short* v_bf  = k_bf + NQ;
  unsigned short* vt_bf = v_bf + NQ;
  float* o_ws   = (float*)(vt_bf + NQ);       // NP_ * NQ floats (partials)
  float* s_part = o_ws + (size_t)NP_ * NQ;    // SZ_ * BH_ * T_ floats

  proj_kernel<<<dim3(B_ * T_ / 8, 3), 512, 0, stream>>>(
      queries, keys, values, Wq, Wk, Wv, q_bf, k_bf, v_bf);
  stats_kernel<<<T_ / 256 * BH_ * SZ_, 256, 0, stream>>>(k_bf, q_bf, s_part);
  scale_kernel<<<dim3(T_ / 64, BH_), 256, 0, stream>>>(v_bf, s_part, vt_bf);
  apply_kernel<<<BH_ * (T_ / 128) * NP_, 256, 0, stream>>>(k_bf, q_bf, vt_bf, o_ws);
  unify_kernel<<<B_ * T_ / 16, 256, 0, stream>>>(o_ws, o_ws + NQ, Wu, bu, out);
}